// Round 2
// baseline (248.918 us; speedup 1.0000x reference)
//
#include <hip/hip_runtime.h>
#include <math.h>

#define HH 256
#define WW 256
#define NB 4
#define NN 256
#define NSTEPS 50
#define STEPSZ 0.1f
#define ALPHA 0.01f
#define BETA 0.005f
#define DMAX 15.0f
#define TILE 8
#define HROWS (TILE + 12)   // 20 staged rows per block

struct Flt { float g[13]; float dg[13]; };

// Fused separable conv: one block = TILE output rows x 256 cols of one batch.
// Stage pd rows (zero halo) -> horizontal 4-channel conv in LDS -> vertical.
// Outputs two float2 images: imgF = (gimg ch0, ch1), imgW = (gimgW ch0, ch1).
__global__ void conv_fused_kernel(const float* __restrict__ pd,
                                  float2* __restrict__ imgF,
                                  float2* __restrict__ imgW, Flt flt) {
    int blk = blockIdx.x;             // b*(HH/TILE) + tile
    int b = blk / (HH / TILE);
    int t = blk % (HH / TILE);
    int y0 = t * TILE;
    int x = threadIdx.x;
    extern __shared__ char smem[];
    float (*srow)[WW + 16] = (float (*)[WW + 16])smem;               // 20x272 f32
    float4* hbuf = (float4*)(smem + HROWS * (WW + 16) * sizeof(float)); // 20x256 f32x4

    for (int r = 0; r < HROWS; ++r) {
        int yy = y0 - 6 + r;
        float v = 0.f;
        if (yy >= 0 && yy < HH) v = pd[((size_t)b * HH + yy) * WW + x];
        srow[r][6 + x] = v;
        if (x < 6) { srow[r][x] = 0.f; srow[r][WW + 6 + x] = 0.f; }
    }
    __syncthreads();
    for (int r = 0; r < HROWS; ++r) {
        float sg = 0.f, sdg = 0.f, sga = 0.f, sdga = 0.f;
#pragma unroll
        for (int j = 0; j < 13; ++j) {
            float v = srow[r][x + j];
            float a = fabsf(v);
            sg   += flt.g[j]  * v;
            sdg  += flt.dg[j] * v;
            sga  += flt.g[j]  * a;
            sdga += flt.dg[j] * a;
        }
        hbuf[r * WW + x] = make_float4(sg, sdg, sga, sdga);
    }
    __syncthreads();
    for (int r = 0; r < TILE; ++r) {
        float g0 = 0.f, g1 = 0.f, w0 = 0.f, w1 = 0.f;
#pragma unroll
        for (int i = 0; i < 13; ++i) {
            float4 v = hbuf[(r + i) * WW + x];
            g0 += flt.dg[i] * v.x;    // fy: dg over y of (g over x)
            g1 += flt.g[i]  * v.y;    // fx: g over y of (dg over x)
            w0 += flt.dg[i] * v.z;
            w1 += flt.g[i]  * v.w;
        }
        size_t o = ((size_t)b * HH + y0 + r) * WW + x;
        imgF[o] = make_float2(10.f * g0, 10.f * g1);
        imgW[o] = make_float2(10.f * w0, 10.f * w1);
    }
}

// Bilinear sample of a 2-channel float2 image. Corner pairs (x0,x0+1) are
// 16 contiguous bytes -> one (possibly 8B-aligned) 16B load per row.
__device__ __forceinline__ void bilin2(const float2* __restrict__ img,
                                       float py_, float px_,
                                       float& o0, float& o1) {
    float yc = fminf(fmaxf(py_, 0.f), 254.999f);
    float xc = fminf(fmaxf(px_, 0.f), 254.999f);
    int y0 = (int)yc, x0 = (int)xc;
    float ty = yc - (float)y0;
    float tx = xc - (float)x0;
    const float2* p = img + (size_t)y0 * WW + x0;
    float4 r0, r1;
    __builtin_memcpy(&r0, p, 16);
    __builtin_memcpy(&r1, p + WW, 16);
    float w00 = (1.f - ty) * (1.f - tx), w01 = (1.f - ty) * tx;
    float w10 = ty * (1.f - tx),         w11 = ty * tx;
    o0 = r0.x * w00 + r0.z * w01 + r1.x * w10 + r1.z * w11;
    o1 = r0.y * w00 + r0.w * w01 + r1.y * w10 + r1.w * w11;
}

// One wave per batch. 4 nodes per lane, all state in registers; neighbor
// exchange via shuffles. Zero barriers, zero LDS.
__global__ void snake_kernel(const float2* __restrict__ imgF,
                             const float2* __restrict__ imgW,
                             const float* __restrict__ node_pos,
                             const float* __restrict__ widths,
                             float4* __restrict__ nodes_out) {
    int b = blockIdx.x;
    int lane = threadIdx.x;   // 0..63
    const float2* iF = imgF + (size_t)b * HH * WW;
    const float2* iW = imgW + (size_t)b * HH * WW;
    float py[4], px[4], wd[4];
    const float2* np2 = (const float2*)(node_pos + (size_t)b * NN * 2);
#pragma unroll
    for (int k = 0; k < 4; ++k) {
        float2 p = np2[lane * 4 + k];
        py[k] = p.x; px[k] = p.y;
        wd[k] = widths[(size_t)b * NN + lane * 4 + k];
    }
    for (int s = 0; s < NSTEPS; ++s) {
        // issue external-force gathers first so they overlap the shuffles
        float fy[4], fx[4];
#pragma unroll
        for (int k = 0; k < 4; ++k) bilin2(iF, py[k], px[k], fy[k], fx[k]);

        float pym = __shfl_up(py[3], 1), pxm = __shfl_up(px[3], 1);
        float pyp = __shfl_down(py[0], 1), pxp = __shfl_down(px[0], 1);
        if (lane == 0)  { pym = py[0]; pxm = px[0]; }
        if (lane == 63) { pyp = py[3]; pxp = px[3]; }
        float d2y[4], d2x[4];
#pragma unroll
        for (int k = 0; k < 4; ++k) {
            float ly = (k == 0) ? pym : py[k - 1];
            float lx = (k == 0) ? pxm : px[k - 1];
            float ry = (k == 3) ? pyp : py[k + 1];
            float rx = (k == 3) ? pxp : px[k + 1];
            d2y[k] = ly - 2.f * py[k] + ry;
            d2x[k] = lx - 2.f * px[k] + rx;
        }
        float qym = __shfl_up(d2y[3], 1), qxm = __shfl_up(d2x[3], 1);
        float qyp = __shfl_down(d2y[0], 1), qxp = __shfl_down(d2x[0], 1);
        if (lane == 0)  { qym = d2y[0]; qxm = d2x[0]; }
        if (lane == 63) { qyp = d2y[3]; qxp = d2x[3]; }
#pragma unroll
        for (int k = 0; k < 4; ++k) {
            float ly = (k == 0) ? qym : d2y[k - 1];
            float lx = (k == 0) ? qxm : d2x[k - 1];
            float ry = (k == 3) ? qyp : d2y[k + 1];
            float rx = (k == 3) ? qxp : d2x[k + 1];
            float d4y = ly - 2.f * d2y[k] + ry;
            float d4x = lx - 2.f * d2x[k] + rx;
            float npy = py[k] + STEPSZ * (ALPHA * d2y[k] - BETA * d4y + fy[k]);
            float npx = px[k] + STEPSZ * (ALPHA * d2x[k] - BETA * d4x + fx[k]);
            py[k] = fminf(fmaxf(npy, 0.f), (float)(HH - 1));
            px[k] = fminf(fmaxf(npx, 0.f), (float)(WW - 1));
        }
        // width force at NEW positions
        float fw[4];
#pragma unroll
        for (int k = 0; k < 4; ++k) {
            float a, c;
            bilin2(iW, py[k], px[k], a, c);
            fw[k] = a + c;
        }
        float wm = __shfl_up(wd[3], 1), wp = __shfl_down(wd[0], 1);
        if (lane == 0)  wm = wd[0];
        if (lane == 63) wp = wd[3];
#pragma unroll
        for (int k = 0; k < 4; ++k) {
            float l = (k == 0) ? wm : wd[k - 1];
            float r = (k == 3) ? wp : wd[k + 1];
            float d2w = l - 2.f * wd[k] + r;
            float nw = wd[k] + STEPSZ * (ALPHA * d2w + fw[k]);
            wd[k] = fminf(fmaxf(nw, 0.f), DMAX);
        }
    }
#pragma unroll
    for (int k = 0; k < 4; ++k)
        nodes_out[(size_t)b * NN + lane * 4 + k] =
            make_float4(py[k], px[k], wd[k], 0.f);
}

// One block = one image row; min over 256 nodes staged in LDS; early exit
// when the wave's running min <= 0 (clip floor). Per-row partial sums.
__global__ void render_loss_kernel(const float* __restrict__ pd,
                                   const float4* __restrict__ nodes,
                                   float* __restrict__ partial) {
    int row = blockIdx.x;                  // b*H + y
    int b = row / HH;
    int y = row % HH;
    int x = threadIdx.x;
    __shared__ float4 nd[NN];
    nd[x] = nodes[(size_t)b * NN + x];
    __syncthreads();
    float fyc = (float)y, fxc = (float)x;
    float m = 1e30f;
    for (int n0 = 0; n0 < NN; n0 += 32) {
#pragma unroll
        for (int n = n0; n < n0 + 32; ++n) {
            float4 p = nd[n];
            float dy = fyc - p.x;
            float dx = fxc - p.y;
            float d = sqrtf(dy * dy + dx * dx) - p.z;
            m = fminf(m, d);
        }
        if (__all(m <= 0.f)) break;        // clip floor: result is 0 for all lanes
    }
    float dm = fminf(fmaxf(m, 0.f), DMAX);
    float diff = pd[(size_t)row * WW + x] - dm;
    float v = diff * diff;
    for (int off = 32; off > 0; off >>= 1) v += __shfl_down(v, off, 64);
    __shared__ float wsum[4];
    if ((x & 63) == 0) wsum[x >> 6] = v;
    __syncthreads();
    if (x == 0) partial[row] = wsum[0] + wsum[1] + wsum[2] + wsum[3];
}

__global__ void finalize_kernel(const float* __restrict__ partial,
                                float* __restrict__ out) {
    int t = threadIdx.x;  // 256
    float v = partial[t] + partial[t + 256] + partial[t + 512] + partial[t + 768];
    for (int off = 32; off > 0; off >>= 1) v += __shfl_down(v, off, 64);
    __shared__ float wsum[4];
    if ((t & 63) == 0) wsum[t >> 6] = v;
    __syncthreads();
    if (t == 0)
        out[0] = (wsum[0] + wsum[1] + wsum[2] + wsum[3]) *
                 (1.f / (float)(NB * HH * WW));
}

extern "C" void kernel_launch(void* const* d_in, const int* in_sizes, int n_in,
                              void* d_out, int out_size, void* d_ws, size_t ws_size,
                              hipStream_t stream) {
    const float* pd       = (const float*)d_in[0];   // (B,1,H,W)
    const float* node_pos = (const float*)d_in[1];   // (B,N,2)
    const float* widths   = (const float*)d_in[2];   // (B,N)
    float* out = (float*)d_out;

    char* ws = (char*)d_ws;
    size_t img2_bytes = (size_t)NB * HH * WW * sizeof(float2);  // 2 MB each
    float2* imgF   = (float2*)ws;
    float2* imgW   = (float2*)(ws + img2_bytes);
    float4* nodes  = (float4*)(ws + 2 * img2_bytes);
    float*  partial = (float*)(ws + 2 * img2_bytes + (size_t)NB * NN * sizeof(float4));

    Flt flt;
    {
        float g[13];
        float s = 0.f;
        for (int i = 0; i < 13; ++i) {
            float xx = (float)(i - 6);
            g[i] = expf(-xx * xx / 8.f);
            s += g[i];
        }
        for (int i = 0; i < 13; ++i) {
            flt.g[i]  = g[i] / s;
            flt.dg[i] = -(float)(i - 6) / 4.f * flt.g[i];
        }
    }

    size_t conv_lds = (size_t)HROWS * (WW + 16) * sizeof(float)
                    + (size_t)HROWS * WW * sizeof(float4);      // ~103 KB
    conv_fused_kernel<<<NB * (HH / TILE), WW, conv_lds, stream>>>(pd, imgF, imgW, flt);
    snake_kernel<<<NB, 64, 0, stream>>>(imgF, imgW, node_pos, widths, nodes);
    render_loss_kernel<<<NB * HH, WW, 0, stream>>>(pd, nodes, partial);
    finalize_kernel<<<1, 256, 0, stream>>>(partial, out);
}

// Round 3
// 188.068 us; speedup vs baseline: 1.3236x; 1.3236x over previous
//
#include <hip/hip_runtime.h>
#include <math.h>

#define HH 256
#define WW 256
#define NB 4
#define NN 256
#define NSTEPS 50
#define STEPSZ 0.1f
#define ALPHA 0.01f
#define BETA 0.005f
#define DMAX 15.0f
#define TILE 8
#define HROWS (TILE + 12)   // 20 staged rows per block

struct Flt { float g[13]; float dg[13]; };

// Fused separable conv: one block = TILE output rows x 256 cols of one batch.
// Output float4 per pixel: (gimg_y, gimg_x, gimgW_y, gimgW_x) * EXTGRADFAC.
__global__ void conv_fused_kernel(const float* __restrict__ pd,
                                  float4* __restrict__ img4, Flt flt) {
    int blk = blockIdx.x;             // b*(HH/TILE) + tile
    int b = blk / (HH / TILE);
    int t = blk % (HH / TILE);
    int y0 = t * TILE;
    int x = threadIdx.x;
    extern __shared__ char smem[];
    float (*srow)[WW + 16] = (float (*)[WW + 16])smem;                  // 20x272 f32
    float4* hbuf = (float4*)(smem + HROWS * (WW + 16) * sizeof(float)); // 20x256 f32x4

    for (int r = 0; r < HROWS; ++r) {
        int yy = y0 - 6 + r;
        float v = 0.f;
        if (yy >= 0 && yy < HH) v = pd[((size_t)b * HH + yy) * WW + x];
        srow[r][6 + x] = v;
        if (x < 6) { srow[r][x] = 0.f; srow[r][WW + 6 + x] = 0.f; }
    }
    __syncthreads();
    for (int r = 0; r < HROWS; ++r) {
        float sg = 0.f, sdg = 0.f, sga = 0.f, sdga = 0.f;
#pragma unroll
        for (int j = 0; j < 13; ++j) {
            float v = srow[r][x + j];
            float a = fabsf(v);
            sg   += flt.g[j]  * v;
            sdg  += flt.dg[j] * v;
            sga  += flt.g[j]  * a;
            sdga += flt.dg[j] * a;
        }
        hbuf[r * WW + x] = make_float4(sg, sdg, sga, sdga);
    }
    __syncthreads();
    for (int r = 0; r < TILE; ++r) {
        float g0 = 0.f, g1 = 0.f, w0 = 0.f, w1 = 0.f;
#pragma unroll
        for (int i = 0; i < 13; ++i) {
            float4 v = hbuf[(r + i) * WW + x];
            g0 += flt.dg[i] * v.x;    // fy: dg over y of (g over x)
            g1 += flt.g[i]  * v.y;    // fx: g over y of (dg over x)
            w0 += flt.dg[i] * v.z;
            w1 += flt.g[i]  * v.w;
        }
        img4[((size_t)b * HH + y0 + r) * WW + x] =
            make_float4(10.f * g0, 10.f * g1, 10.f * w0, 10.f * w1);
    }
}

// Bilinear sample of the interleaved float4 image: returns the two position-
// force channels and the summed width-force channel. 4x dwordx4 loads.
__device__ __forceinline__ void sample4(const float4* __restrict__ img,
                                        float py_, float px_,
                                        float& fy, float& fx, float& fw) {
    float yc = fminf(fmaxf(py_, 0.f), 254.999f);
    float xc = fminf(fmaxf(px_, 0.f), 254.999f);
    int y0 = (int)yc, x0 = (int)xc;
    float ty = yc - (float)y0, tx = xc - (float)x0;
    const float4* p = img + y0 * WW + x0;
    float4 a0 = p[0], a1 = p[1], b0 = p[WW], b1 = p[WW + 1];
    float w00 = (1.f - ty) * (1.f - tx), w01 = (1.f - ty) * tx;
    float w10 = ty * (1.f - tx),         w11 = ty * tx;
    fy = a0.x * w00 + a1.x * w01 + b0.x * w10 + b1.x * w11;
    fx = a0.y * w00 + a1.y * w01 + b0.y * w10 + b1.y * w11;
    fw = (a0.z + a0.w) * w00 + (a1.z + a1.w) * w01 +
         (b0.z + b0.w) * w10 + (b1.z + b1.w) * w11;
}

// One block (4 waves) per batch, one node per thread. ONE gather round and
// ONE barrier per step: the W-gather at p_new doubles as next step's F-gather
// (same address, interleaved channels); d4 computed locally from p[i-2..i+2]
// (redundant d2) so no second LDS exchange; LDS state double-buffered.
__global__ void snake_kernel(const float4* __restrict__ img4,
                             const float* __restrict__ node_pos,
                             const float* __restrict__ widths,
                             float4* __restrict__ nodes_out,
                             unsigned* __restrict__ cnt) {
    int b = blockIdx.x;
    int i = threadIdx.x;
    if (b == 0 && i == 0) *cnt = 0;   // zero render's done-counter (runs before)
    __shared__ float2 pbuf[2][NN];
    __shared__ float  wbuf[2][NN];
    const float4* img = img4 + (size_t)b * HH * WW;
    const float2* np2 = (const float2*)(node_pos + (size_t)b * NN * 2);
    float2 pc = np2[i];
    float wc = widths[(size_t)b * NN + i];
    pbuf[0][i] = pc;
    wbuf[0][i] = wc;
    int im1 = (i > 0) ? i - 1 : 0;
    int im2 = (i > 1) ? i - 2 : 0;
    int ip1 = (i < NN - 1) ? i + 1 : NN - 1;
    int ip2 = (i < NN - 2) ? i + 2 : NN - 1;
    float fy, fx, fw;
    sample4(img, pc.x, pc.y, fy, fx, fw);   // initial force; fw discarded
    __syncthreads();
    int cur = 0;
    for (int s = 0; s < NSTEPS; ++s) {
        float2 pm2 = pbuf[cur][im2], pm1 = pbuf[cur][im1];
        float2 pp1 = pbuf[cur][ip1], pp2 = pbuf[cur][ip2];
        float wm1 = wbuf[cur][im1], wp1 = wbuf[cur][ip1];
        float d2y = pm1.x - 2.f * pc.x + pp1.x;
        float d2x = pm1.y - 2.f * pc.y + pp1.y;
        float d2my = pm2.x - 2.f * pm1.x + pc.x;   // d2 at index im1
        float d2mx = pm2.y - 2.f * pm1.y + pc.y;
        float d2py = pc.x - 2.f * pp1.x + pp2.x;   // d2 at index ip1
        float d2px = pc.y - 2.f * pp1.y + pp2.y;
        if (i == 0)      { d2my = d2y; d2mx = d2x; }
        if (i == NN - 1) { d2py = d2y; d2px = d2x; }
        float d4y = d2my - 2.f * d2y + d2py;
        float d4x = d2mx - 2.f * d2x + d2px;
        pc.x = fminf(fmaxf(pc.x + STEPSZ * (ALPHA * d2y - BETA * d4y + fy), 0.f),
                     (float)(HH - 1));
        pc.y = fminf(fmaxf(pc.y + STEPSZ * (ALPHA * d2x - BETA * d4x + fx), 0.f),
                     (float)(WW - 1));
        int nxt = cur ^ 1;
        pbuf[nxt][i] = pc;
        sample4(img, pc.x, pc.y, fy, fx, fw);   // W force now + F force for s+1
        float d2w = wm1 - 2.f * wc + wp1;
        wc = fminf(fmaxf(wc + STEPSZ * (ALPHA * d2w + fw), 0.f), DMAX);
        wbuf[nxt][i] = wc;
        cur = nxt;
        __syncthreads();
    }
    nodes_out[(size_t)b * NN + i] = make_float4(pc.x, pc.y, wc, 0.f);
}

// One block = one image row; min over 256 nodes (LDS); per-row partial sum;
// last finishing block reduces all partials (device-scope atomics).
__global__ void render_loss_kernel(const float* __restrict__ pd,
                                   const float4* __restrict__ nodes,
                                   float* __restrict__ partial,
                                   unsigned* __restrict__ cnt,
                                   float* __restrict__ out) {
    int row = blockIdx.x;                  // b*H + y
    int b = row / HH;
    int y = row % HH;
    int x = threadIdx.x;
    __shared__ float4 nd[NN];
    nd[x] = nodes[(size_t)b * NN + x];
    __syncthreads();
    float fyc = (float)y, fxc = (float)x;
    float m = 1e30f;
#pragma unroll 8
    for (int n = 0; n < NN; ++n) {
        float4 p = nd[n];
        float dy = fyc - p.x;
        float dx = fxc - p.y;
        float d = sqrtf(dy * dy + dx * dx) - p.z;
        m = fminf(m, d);
    }
    float dm = fminf(fmaxf(m, 0.f), DMAX);
    float diff = pd[(size_t)row * WW + x] - dm;
    float v = diff * diff;
    for (int off = 32; off > 0; off >>= 1) v += __shfl_down(v, off, 64);
    __shared__ float wsum[4];
    __shared__ int lastflag;
    if ((x & 63) == 0) wsum[x >> 6] = v;
    __syncthreads();
    if (x == 0) {
        float s = wsum[0] + wsum[1] + wsum[2] + wsum[3];
        __hip_atomic_store(&partial[row], s, __ATOMIC_RELEASE,
                           __HIP_MEMORY_SCOPE_AGENT);
        unsigned t = __hip_atomic_fetch_add(cnt, 1u, __ATOMIC_ACQ_REL,
                                            __HIP_MEMORY_SCOPE_AGENT);
        lastflag = (t == (unsigned)(NB * HH - 1));
    }
    __syncthreads();
    if (lastflag) {
        float v2 = 0.f;
        for (int j = x; j < NB * HH; j += 256)
            v2 += __hip_atomic_load(&partial[j], __ATOMIC_ACQUIRE,
                                    __HIP_MEMORY_SCOPE_AGENT);
        for (int off = 32; off > 0; off >>= 1) v2 += __shfl_down(v2, off, 64);
        if ((x & 63) == 0) wsum[x >> 6] = v2;
        __syncthreads();
        if (x == 0)
            out[0] = (wsum[0] + wsum[1] + wsum[2] + wsum[3]) *
                     (1.f / (float)(NB * HH * WW));
    }
}

extern "C" void kernel_launch(void* const* d_in, const int* in_sizes, int n_in,
                              void* d_out, int out_size, void* d_ws, size_t ws_size,
                              hipStream_t stream) {
    const float* pd       = (const float*)d_in[0];   // (B,1,H,W)
    const float* node_pos = (const float*)d_in[1];   // (B,N,2)
    const float* widths   = (const float*)d_in[2];   // (B,N)
    float* out = (float*)d_out;

    char* ws = (char*)d_ws;
    size_t img_bytes = (size_t)NB * HH * WW * sizeof(float4);   // 4 MB
    float4*   img4    = (float4*)ws;
    float4*   nodes   = (float4*)(ws + img_bytes);
    float*    partial = (float*)(ws + img_bytes + (size_t)NB * NN * sizeof(float4));
    unsigned* cnt     = (unsigned*)(partial + NB * HH);

    Flt flt;
    {
        float g[13];
        float s = 0.f;
        for (int i = 0; i < 13; ++i) {
            float xx = (float)(i - 6);
            g[i] = expf(-xx * xx / 8.f);
            s += g[i];
        }
        for (int i = 0; i < 13; ++i) {
            flt.g[i]  = g[i] / s;
            flt.dg[i] = -(float)(i - 6) / 4.f * flt.g[i];
        }
    }

    size_t conv_lds = (size_t)HROWS * (WW + 16) * sizeof(float)
                    + (size_t)HROWS * WW * sizeof(float4);      // ~103 KB
    conv_fused_kernel<<<NB * (HH / TILE), WW, conv_lds, stream>>>(pd, img4, flt);
    snake_kernel<<<NB, NN, 0, stream>>>(img4, node_pos, widths, nodes, cnt);
    render_loss_kernel<<<NB * HH, WW, 0, stream>>>(pd, nodes, partial, cnt, out);
}

// Round 4
// 127.463 us; speedup vs baseline: 1.9529x; 1.4755x over previous
//
#include <hip/hip_runtime.h>
#include <hip/hip_fp16.h>
#include <math.h>

#define HH 256
#define WW 256
#define NB 4
#define NN 256
#define NSTEPS 50
#define STEPSZ 0.1f
#define ALPHA 0.01f
#define BETA 0.005f
#define DMAX 15.0f
#define CTILE 4
#define CH (CTILE + 12)     // 16 staged rows per conv block

struct Flt { float g[13]; float dg[13]; };

// Fused separable conv, TILE=4 rows/block, vertical accumulation in registers.
// Output per pixel: half4 (fy, fx, fw0+fw1, 0) * EXTGRADFAC, 8 B.
__global__ void conv_fused_kernel(const float* __restrict__ pd,
                                  uint2* __restrict__ imgH, Flt flt) {
    int blk = blockIdx.x;           // b*64 + tile
    int b = blk >> 6;
    int t = blk & 63;
    int y0 = t * CTILE;
    int x = threadIdx.x;
    __shared__ float srow[CH][WW + 16];
    for (int r = 0; r < CH; ++r) {
        int yy = y0 - 6 + r;
        float v = (yy >= 0 && yy < HH) ? pd[((size_t)b * HH + yy) * WW + x] : 0.f;
        srow[r][6 + x] = v;
        if (x < 6) { srow[r][x] = 0.f; srow[r][WW + 6 + x] = 0.f; }
    }
    __syncthreads();
    float4 h[CH];
#pragma unroll
    for (int r = 0; r < CH; ++r) {
        float sg = 0.f, sdg = 0.f, sga = 0.f, sdga = 0.f;
#pragma unroll
        for (int j = 0; j < 13; ++j) {
            float v = srow[r][x + j];
            float a = fabsf(v);
            sg   += flt.g[j]  * v;
            sdg  += flt.dg[j] * v;
            sga  += flt.g[j]  * a;
            sdga += flt.dg[j] * a;
        }
        h[r] = make_float4(sg, sdg, sga, sdga);
    }
#pragma unroll
    for (int rr = 0; rr < CTILE; ++rr) {
        float g0 = 0.f, g1 = 0.f, w0 = 0.f, w1 = 0.f;
#pragma unroll
        for (int i2 = 0; i2 < 13; ++i2) {
            float4 v = h[rr + i2];
            g0 += flt.dg[i2] * v.x;   // fy: dg over y of (g over x)
            g1 += flt.g[i2]  * v.y;   // fx: g over y of (dg over x)
            w0 += flt.dg[i2] * v.z;
            w1 += flt.g[i2]  * v.w;
        }
        union { uint2 u; __half hh[4]; } o;
        o.hh[0] = __float2half(10.f * g0);
        o.hh[1] = __float2half(10.f * g1);
        o.hh[2] = __float2half(10.f * (w0 + w1));  // width force pre-summed (linear)
        o.hh[3] = __float2half(0.f);
        imgH[((size_t)b * HH + y0 + rr) * WW + x] = o.u;
    }
}

// Bilinear sample of the half4 image: TWO dwordx4 loads (2 px * 8 B per row).
__device__ __forceinline__ void sampleH(const uint2* __restrict__ img,
                                        float py_, float px_,
                                        float& fy, float& fx, float& fw) {
    float yc = fminf(fmaxf(py_, 0.f), 254.999f);
    float xc = fminf(fmaxf(px_, 0.f), 254.999f);
    int y0 = (int)yc, x0 = (int)xc;
    float ty = yc - (float)y0, tx = xc - (float)x0;
    const uint2* p = img + y0 * WW + x0;
    union { uint4 u; __half h[8]; } r0, r1;
    r0.u = *(const uint4*)p;          // (y0,x0),(y0,x0+1) — 16 B
    r1.u = *(const uint4*)(p + WW);   // (y0+1,x0),(y0+1,x0+1)
    float w00 = (1.f - ty) * (1.f - tx), w01 = (1.f - ty) * tx;
    float w10 = ty * (1.f - tx),         w11 = ty * tx;
    fy = __half2float(r0.h[0]) * w00 + __half2float(r0.h[4]) * w01 +
         __half2float(r1.h[0]) * w10 + __half2float(r1.h[4]) * w11;
    fx = __half2float(r0.h[1]) * w00 + __half2float(r0.h[5]) * w01 +
         __half2float(r1.h[1]) * w10 + __half2float(r1.h[5]) * w11;
    fw = __half2float(r0.h[2]) * w00 + __half2float(r0.h[6]) * w01 +
         __half2float(r1.h[2]) * w10 + __half2float(r1.h[6]) * w11;
}

// One block (4 waves) per batch, one node per thread. One gather + one barrier
// per step; the w-update is pipelined one iteration so the gather result is
// consumed AFTER the barrier (latency overlaps barrier drain, not exposed).
__global__ void snake_kernel(const uint2* __restrict__ imgH,
                             const float* __restrict__ node_pos,
                             const float* __restrict__ widths,
                             float4* __restrict__ nodes_out,
                             unsigned* __restrict__ cnt) {
    int b = blockIdx.x;
    int i = threadIdx.x;
    if (b == 0 && i == 0) *cnt = 0;   // zero render's done-counter
    __shared__ float2 pbuf[2][NN];
    __shared__ float  wbuf[2][NN];
    const uint2* img = imgH + (size_t)b * HH * WW;
    const float2* np2 = (const float2*)(node_pos + (size_t)b * NN * 2);
    float2 pc = np2[i];
    float wc = widths[(size_t)b * NN + i];
    pbuf[0][i] = pc;
    wbuf[0][i] = wc;
    int im1 = (i > 0) ? i - 1 : 0;
    int im2 = (i > 1) ? i - 2 : 0;
    int ip1 = (i < NN - 1) ? i + 1 : NN - 1;
    int ip2 = (i < NN - 2) ? i + 2 : NN - 1;
    float fy, fx, fw;
    sampleH(img, pc.x, pc.y, fy, fx, fw);   // force at p_0 (fw unused at s=0)
    __syncthreads();
    int cur = 0;
    for (int s = 0; s < NSTEPS; ++s) {
        int nxt = cur ^ 1;
        // w_s = w_{s-1} + dt*(ALPHA*d2(w_{s-1}) + fw@p_s)   [skip at s=0]
        float wm1 = wbuf[cur][im1], wp1 = wbuf[cur][ip1];
        float d2w = wm1 - 2.f * wc + wp1;
        if (s) wc = fminf(fmaxf(wc + STEPSZ * (ALPHA * d2w + fw), 0.f), DMAX);
        wbuf[nxt][i] = wc;
        // p_{s+1} from p_s neighbors + force at p_s
        float2 pm2 = pbuf[cur][im2], pm1 = pbuf[cur][im1];
        float2 pp1 = pbuf[cur][ip1], pp2 = pbuf[cur][ip2];
        float d2y = pm1.x - 2.f * pc.x + pp1.x;
        float d2x = pm1.y - 2.f * pc.y + pp1.y;
        float d2my = pm2.x - 2.f * pm1.x + pc.x;
        float d2mx = pm2.y - 2.f * pm1.y + pc.y;
        float d2py = pc.x - 2.f * pp1.x + pp2.x;
        float d2px = pc.y - 2.f * pp1.y + pp2.y;
        if (i == 0)      { d2my = d2y; d2mx = d2x; }
        if (i == NN - 1) { d2py = d2y; d2px = d2x; }
        float d4y = d2my - 2.f * d2y + d2py;
        float d4x = d2mx - 2.f * d2x + d2px;
        pc.x = fminf(fmaxf(pc.x + STEPSZ * (ALPHA * d2y - BETA * d4y + fy), 0.f),
                     (float)(HH - 1));
        pc.y = fminf(fmaxf(pc.y + STEPSZ * (ALPHA * d2x - BETA * d4x + fx), 0.f),
                     (float)(WW - 1));
        pbuf[nxt][i] = pc;
        sampleH(img, pc.x, pc.y, fy, fx, fw);  // consumed next iter, after barrier
        cur = nxt;
        __syncthreads();
    }
    // final pending w update: w_NSTEPS from d2(w_{NSTEPS-1}) + fw@p_NSTEPS
    float wm1 = wbuf[cur][im1], wp1 = wbuf[cur][ip1];
    float d2w = wm1 - 2.f * wc + wp1;
    wc = fminf(fmaxf(wc + STEPSZ * (ALPHA * d2w + fw), 0.f), DMAX);
    nodes_out[(size_t)b * NN + i] = make_float4(pc.x, pc.y, wc, 0.f);
}

// One block = 32x8 px tile. Cull nodes to the tile (rect distance < 15+w),
// compact into LDS, then scan with running-threshold test — sqrt only on
// strict improvements. Last finishing block reduces all partials.
__global__ void render_loss_kernel(const float* __restrict__ pd,
                                   const float4* __restrict__ nodes,
                                   float* __restrict__ partial,
                                   unsigned* __restrict__ cnt,
                                   float* __restrict__ out) {
    int blk = blockIdx.x;
    int b = blk >> 8;                 // 256 tiles per batch
    int tile = blk & 255;
    int tx0 = (tile & 7) << 5;        // 8 tiles across, 32 px wide
    int ty0 = (tile >> 3) << 3;       // 32 tiles down, 8 px tall
    int t = threadIdx.x;
    int lx = t & 31, ly = t >> 5;
    __shared__ float4 list[NN];
    __shared__ int wbase[4];
    __shared__ int total;
    __shared__ float wsum[4];
    __shared__ int lastflag;

    // cull: node can produce a value < DMAX somewhere in this tile?
    float4 nv = nodes[(size_t)b * NN + t];
    float ddx = fmaxf(fabsf(nv.y - ((float)tx0 + 15.5f)) - 15.5f, 0.f);
    float ddy = fmaxf(fabsf(nv.x - ((float)ty0 + 3.5f)) - 3.5f, 0.f);
    float rad = DMAX + nv.z;
    bool cand = (ddx * ddx + ddy * ddy) < rad * rad;
    unsigned long long mask = __ballot(cand);
    int wid = t >> 6;
    if ((t & 63) == 0) wbase[wid] = __popcll(mask);
    __syncthreads();
    if (t == 0) {
        int s = 0;
#pragma unroll
        for (int wv = 0; wv < 4; ++wv) { int c = wbase[wv]; wbase[wv] = s; s += c; }
        total = s;
    }
    __syncthreads();
    if (cand) {
        int pos = wbase[wid] + __popcll(mask & ((1ULL << (t & 63)) - 1ULL));
        list[pos] = nv;
    }
    __syncthreads();

    float fyc = (float)(ty0 + ly), fxc = (float)(tx0 + lx);
    float v = DMAX;                   // non-candidates can't beat DMAX
    int tot = total;
    for (int j = 0; j < tot; ++j) {
        float4 p = list[j];
        float dy = fyc - p.x;
        float dx = fxc - p.y;
        float r2 = dy * dy + dx * dx;
        float tt = v + p.z;
        if (tt > 0.f && r2 < tt * tt)   // beats current best
            v = sqrtf(r2) - p.z;
    }
    float dm = fmaxf(v, 0.f);           // v <= DMAX already
    float diff = pd[((size_t)b * HH + ty0 + ly) * WW + tx0 + lx] - dm;
    float val = diff * diff;
    for (int off = 32; off > 0; off >>= 1) val += __shfl_down(val, off, 64);
    if ((t & 63) == 0) wsum[wid] = val;
    __syncthreads();
    if (t == 0) {
        float s = wsum[0] + wsum[1] + wsum[2] + wsum[3];
        __hip_atomic_store(&partial[blk], s, __ATOMIC_RELEASE,
                           __HIP_MEMORY_SCOPE_AGENT);
        unsigned c = __hip_atomic_fetch_add(cnt, 1u, __ATOMIC_ACQ_REL,
                                            __HIP_MEMORY_SCOPE_AGENT);
        lastflag = (c == (unsigned)(NB * 256 - 1));
    }
    __syncthreads();
    if (lastflag) {
        float v2 = 0.f;
        for (int j = t; j < NB * 256; j += 256)
            v2 += __hip_atomic_load(&partial[j], __ATOMIC_ACQUIRE,
                                    __HIP_MEMORY_SCOPE_AGENT);
        for (int off = 32; off > 0; off >>= 1) v2 += __shfl_down(v2, off, 64);
        if ((t & 63) == 0) wsum[wid] = v2;
        __syncthreads();
        if (t == 0)
            out[0] = (wsum[0] + wsum[1] + wsum[2] + wsum[3]) *
                     (1.f / (float)(NB * HH * WW));
    }
}

extern "C" void kernel_launch(void* const* d_in, const int* in_sizes, int n_in,
                              void* d_out, int out_size, void* d_ws, size_t ws_size,
                              hipStream_t stream) {
    const float* pd       = (const float*)d_in[0];   // (B,1,H,W)
    const float* node_pos = (const float*)d_in[1];   // (B,N,2)
    const float* widths   = (const float*)d_in[2];   // (B,N)
    float* out = (float*)d_out;

    char* ws = (char*)d_ws;
    size_t img_bytes = (size_t)NB * HH * WW * sizeof(uint2);    // 2 MB
    uint2*    imgH    = (uint2*)ws;
    float4*   nodes   = (float4*)(ws + img_bytes);
    float*    partial = (float*)(ws + img_bytes + (size_t)NB * NN * sizeof(float4));
    unsigned* cnt     = (unsigned*)(partial + NB * 256);

    Flt flt;
    {
        float g[13];
        float s = 0.f;
        for (int i = 0; i < 13; ++i) {
            float xx = (float)(i - 6);
            g[i] = expf(-xx * xx / 8.f);
            s += g[i];
        }
        for (int i = 0; i < 13; ++i) {
            flt.g[i]  = g[i] / s;
            flt.dg[i] = -(float)(i - 6) / 4.f * flt.g[i];
        }
    }

    conv_fused_kernel<<<NB * 64, 256, 0, stream>>>(pd, imgH, flt);
    snake_kernel<<<NB, NN, 0, stream>>>(imgH, node_pos, widths, nodes, cnt);
    render_loss_kernel<<<NB * 256, 256, 0, stream>>>(pd, nodes, partial, cnt, out);
}

// Round 5
// 125.137 us; speedup vs baseline: 1.9892x; 1.0186x over previous
//
#include <hip/hip_runtime.h>
#include <hip/hip_fp16.h>
#include <math.h>

#define HH 256
#define WW 256
#define NB 4
#define NN 256
#define NSTEPS 50
#define STEPSZ 0.1f
#define ALPHA 0.01f
#define BETA 0.005f
#define DMAX 15.0f
#define CTILE 4
#define CH (CTILE + 1 + 12)   // 17 staged rows: need CTILE+1 vertical results

struct Flt { float g[13]; float dg[13]; };

// Fused separable conv producing PRE-GATHERED bilinear records:
// per pixel (y,x) a 32B-aligned record with the 4 corner values
// (fy,fx,fw) at (y,x),(y,x+1),(y+1,x),(y+1,x+1) as 12 halfs (24B + pad).
// One snake sample then reads ONE cache line.
__global__ void conv_fused_kernel(const float* __restrict__ pd,
                                  uint4* __restrict__ rec, Flt flt) {
    int blk = blockIdx.x;           // b*64 + tile
    int b = blk >> 6;
    int t = blk & 63;
    int y0 = t * CTILE;
    int x = threadIdx.x;
    __shared__ float srow[CH][WW + 16];
    __shared__ float vres[CTILE + 1][WW + 2][3];
    for (int r = 0; r < CH; ++r) {
        int yy = y0 - 6 + r;
        float v = (yy >= 0 && yy < HH) ? pd[((size_t)b * HH + yy) * WW + x] : 0.f;
        srow[r][6 + x] = v;
        if (x < 6) { srow[r][x] = 0.f; srow[r][WW + 6 + x] = 0.f; }
    }
    __syncthreads();
    float4 h[CH];
#pragma unroll
    for (int r = 0; r < CH; ++r) {
        float sg = 0.f, sdg = 0.f, sga = 0.f, sdga = 0.f;
#pragma unroll
        for (int j = 0; j < 13; ++j) {
            float v = srow[r][x + j];
            float a = fabsf(v);
            sg   += flt.g[j]  * v;
            sdg  += flt.dg[j] * v;
            sga  += flt.g[j]  * a;
            sdga += flt.dg[j] * a;
        }
        h[r] = make_float4(sg, sdg, sga, sdga);
    }
#pragma unroll
    for (int rr = 0; rr <= CTILE; ++rr) {
        float g0 = 0.f, g1 = 0.f, w0 = 0.f, w1 = 0.f;
#pragma unroll
        for (int i2 = 0; i2 < 13; ++i2) {
            float4 v = h[rr + i2];
            g0 += flt.dg[i2] * v.x;   // fy: dg over y of (g over x)
            g1 += flt.g[i2]  * v.y;   // fx: g over y of (dg over x)
            w0 += flt.dg[i2] * v.z;
            w1 += flt.g[i2]  * v.w;
        }
        vres[rr][x][0] = 10.f * g0;
        vres[rr][x][1] = 10.f * g1;
        vres[rr][x][2] = 10.f * (w0 + w1);   // width force pre-summed (linear)
    }
    __syncthreads();
#pragma unroll
    for (int rr = 0; rr < CTILE; ++rr) {
        const float* c00 = vres[rr][x];
        const float* c01 = vres[rr][x + 1];       // x=255 reads garbage col; that
        const float* c10 = vres[rr + 1][x];       // record is never sampled
        const float* c11 = vres[rr + 1][x + 1];
        union { uint4 u; __half hh[8]; } lo;
        union { uint2 u; __half hh[4]; } hi;
        lo.hh[0] = __float2half(c00[0]); lo.hh[1] = __float2half(c00[1]);
        lo.hh[2] = __float2half(c00[2]);
        lo.hh[3] = __float2half(c01[0]); lo.hh[4] = __float2half(c01[1]);
        lo.hh[5] = __float2half(c01[2]);
        lo.hh[6] = __float2half(c10[0]); lo.hh[7] = __float2half(c10[1]);
        hi.hh[0] = __float2half(c10[2]);
        hi.hh[1] = __float2half(c11[0]); hi.hh[2] = __float2half(c11[1]);
        hi.hh[3] = __float2half(c11[2]);
        size_t ridx = ((size_t)b * HH + y0 + rr) * WW + x;
        rec[ridx * 2] = lo.u;
        *((uint2*)(rec + ridx * 2 + 1)) = hi.u;
    }
}

// One-cache-line bilinear sample from the pre-gathered record image.
__device__ __forceinline__ void sampleR(const uint4* __restrict__ rec,
                                        float py_, float px_,
                                        float& fy, float& fx, float& fw) {
    float yc = fminf(fmaxf(py_, 0.f), 254.999f);
    float xc = fminf(fmaxf(px_, 0.f), 254.999f);
    int y0 = (int)yc, x0 = (int)xc;
    float ty = yc - (float)y0, tx = xc - (float)x0;
    const uint4* p = rec + (size_t)((y0 << 8) + x0) * 2;
    union { uint4 u; __half h[8]; } lo;
    union { uint2 u; __half h[4]; } hi;
    lo.u = p[0];
    hi.u = *(const uint2*)(p + 1);
    float w00 = (1.f - ty) * (1.f - tx), w01 = (1.f - ty) * tx;
    float w10 = ty * (1.f - tx),         w11 = ty * tx;
    fy = __half2float(lo.h[0]) * w00 + __half2float(lo.h[3]) * w01 +
         __half2float(lo.h[6]) * w10 + __half2float(hi.h[1]) * w11;
    fx = __half2float(lo.h[1]) * w00 + __half2float(lo.h[4]) * w01 +
         __half2float(lo.h[7]) * w10 + __half2float(hi.h[2]) * w11;
    fw = __half2float(lo.h[2]) * w00 + __half2float(lo.h[5]) * w01 +
         __half2float(hi.h[0]) * w10 + __half2float(hi.h[3]) * w11;
}

// One block (4 waves) per batch, one node per thread. One gather + one
// barrier per step; gather result consumed only AFTER the next barrier.
// State packed float4 -> 4x ds_read_b128/step; position update + gather
// issue happen before the w-update ALU.
__global__ void snake_kernel(const uint4* __restrict__ rec,
                             const float* __restrict__ node_pos,
                             const float* __restrict__ widths,
                             float4* __restrict__ nodes_out,
                             unsigned* __restrict__ cnt) {
    int b = blockIdx.x;
    int i = threadIdx.x;
    if (b == 0 && i == 0) *cnt = 0;   // zero render's done-counter
    __shared__ float4 buf[2][NN];
    const uint4* img = rec + (size_t)b * HH * WW * 2;
    const float2* np2 = (const float2*)(node_pos + (size_t)b * NN * 2);
    float2 pc = np2[i];
    float wc = widths[(size_t)b * NN + i];
    buf[0][i] = make_float4(pc.x, pc.y, wc, 0.f);
    int im1 = (i > 0) ? i - 1 : 0;
    int im2 = (i > 1) ? i - 2 : 0;
    int ip1 = (i < NN - 1) ? i + 1 : NN - 1;
    int ip2 = (i < NN - 2) ? i + 2 : NN - 1;
    float fy, fx, fw;
    sampleR(img, pc.x, pc.y, fy, fx, fw);   // force at p_0 (fw unused at s=0)
    __syncthreads();
    int cur = 0;
    for (int s = 0; s < NSTEPS; ++s) {
        int nxt = cur ^ 1;
        float4 m2 = buf[cur][im2], m1 = buf[cur][im1];
        float4 p1 = buf[cur][ip1], p2 = buf[cur][ip2];
        float d2y = m1.x - 2.f * pc.x + p1.x;
        float d2x = m1.y - 2.f * pc.y + p1.y;
        float d2my = m2.x - 2.f * m1.x + pc.x;
        float d2mx = m2.y - 2.f * m1.y + pc.y;
        float d2py = pc.x - 2.f * p1.x + p2.x;
        float d2px = pc.y - 2.f * p1.y + p2.y;
        if (i == 0)      { d2my = d2y; d2mx = d2x; }
        if (i == NN - 1) { d2py = d2y; d2px = d2x; }
        float d4y = d2my - 2.f * d2y + d2py;
        float d4x = d2mx - 2.f * d2x + d2px;
        pc.x = fminf(fmaxf(pc.x + STEPSZ * (ALPHA * d2y - BETA * d4y + fy), 0.f),
                     (float)(HH - 1));
        pc.y = fminf(fmaxf(pc.y + STEPSZ * (ALPHA * d2x - BETA * d4x + fx), 0.f),
                     (float)(WW - 1));
        *((float2*)&buf[nxt][i]) = pc;          // position visible next step
        float nfy, nfx, nfw;
        sampleR(img, pc.x, pc.y, nfy, nfx, nfw);  // issued early; used next iter
        // w_s = w_{s-1} + dt*(ALPHA*d2(w_{s-1}) + fw@p_s)   [skip at s=0]
        float d2w = m1.z - 2.f * wc + p1.z;
        if (s) wc = fminf(fmaxf(wc + STEPSZ * (ALPHA * d2w + fw), 0.f), DMAX);
        buf[nxt][i].z = wc;
        fy = nfy; fx = nfx; fw = nfw;
        cur = nxt;
        __syncthreads();
    }
    // final pending w update with fw@p_NSTEPS
    float wm1 = buf[cur][im1].z, wp1 = buf[cur][ip1].z;
    float d2w = wm1 - 2.f * wc + wp1;
    wc = fminf(fmaxf(wc + STEPSZ * (ALPHA * d2w + fw), 0.f), DMAX);
    nodes_out[(size_t)b * NN + i] = make_float4(pc.x, pc.y, wc, 0.f);
}

// One block = 32x8 px tile. Cull nodes (rect distance < DMAX+w), compact to
// LDS, scan with running-threshold test (sqrt only on improvement). Last
// finishing block reduces all partials.
__global__ void render_loss_kernel(const float* __restrict__ pd,
                                   const float4* __restrict__ nodes,
                                   float* __restrict__ partial,
                                   unsigned* __restrict__ cnt,
                                   float* __restrict__ out) {
    int blk = blockIdx.x;
    int b = blk >> 8;                 // 256 tiles per batch
    int tile = blk & 255;
    int tx0 = (tile & 7) << 5;        // 32 px wide
    int ty0 = (tile >> 3) << 3;       // 8 px tall
    int t = threadIdx.x;
    int lx = t & 31, ly = t >> 5;
    __shared__ float4 list[NN];
    __shared__ int wbase[4];
    __shared__ int total;
    __shared__ float wsum[4];
    __shared__ int lastflag;

    float4 nv = nodes[(size_t)b * NN + t];
    float ddx = fmaxf(fabsf(nv.y - ((float)tx0 + 15.5f)) - 15.5f, 0.f);
    float ddy = fmaxf(fabsf(nv.x - ((float)ty0 + 3.5f)) - 3.5f, 0.f);
    float rad = DMAX + nv.z;
    bool cand = (ddx * ddx + ddy * ddy) < rad * rad;
    unsigned long long mask = __ballot(cand);
    int wid = t >> 6;
    if ((t & 63) == 0) wbase[wid] = __popcll(mask);
    __syncthreads();
    if (t == 0) {
        int s = 0;
#pragma unroll
        for (int wv = 0; wv < 4; ++wv) { int c = wbase[wv]; wbase[wv] = s; s += c; }
        total = s;
    }
    __syncthreads();
    if (cand) {
        int pos = wbase[wid] + __popcll(mask & ((1ULL << (t & 63)) - 1ULL));
        list[pos] = nv;
    }
    __syncthreads();

    float fyc = (float)(ty0 + ly), fxc = (float)(tx0 + lx);
    float v = DMAX;
    int tot = total;
    for (int j = 0; j < tot; ++j) {
        float4 p = list[j];
        float dy = fyc - p.x;
        float dx = fxc - p.y;
        float r2 = dy * dy + dx * dx;
        float tt = v + p.z;
        if (tt > 0.f && r2 < tt * tt)
            v = sqrtf(r2) - p.z;
    }
    float dm = fmaxf(v, 0.f);
    float diff = pd[((size_t)b * HH + ty0 + ly) * WW + tx0 + lx] - dm;
    float val = diff * diff;
    for (int off = 32; off > 0; off >>= 1) val += __shfl_down(val, off, 64);
    if ((t & 63) == 0) wsum[wid] = val;
    __syncthreads();
    if (t == 0) {
        float s = wsum[0] + wsum[1] + wsum[2] + wsum[3];
        __hip_atomic_store(&partial[blk], s, __ATOMIC_RELEASE,
                           __HIP_MEMORY_SCOPE_AGENT);
        unsigned c = __hip_atomic_fetch_add(cnt, 1u, __ATOMIC_ACQ_REL,
                                            __HIP_MEMORY_SCOPE_AGENT);
        lastflag = (c == (unsigned)(NB * 256 - 1));
    }
    __syncthreads();
    if (lastflag) {
        float v2 = 0.f;
        for (int j = t; j < NB * 256; j += 256)
            v2 += __hip_atomic_load(&partial[j], __ATOMIC_ACQUIRE,
                                    __HIP_MEMORY_SCOPE_AGENT);
        for (int off = 32; off > 0; off >>= 1) v2 += __shfl_down(v2, off, 64);
        if ((t & 63) == 0) wsum[wid] = v2;
        __syncthreads();
        if (t == 0)
            out[0] = (wsum[0] + wsum[1] + wsum[2] + wsum[3]) *
                     (1.f / (float)(NB * HH * WW));
    }
}

extern "C" void kernel_launch(void* const* d_in, const int* in_sizes, int n_in,
                              void* d_out, int out_size, void* d_ws, size_t ws_size,
                              hipStream_t stream) {
    const float* pd       = (const float*)d_in[0];   // (B,1,H,W)
    const float* node_pos = (const float*)d_in[1];   // (B,N,2)
    const float* widths   = (const float*)d_in[2];   // (B,N)
    float* out = (float*)d_out;

    char* ws = (char*)d_ws;
    size_t rec_bytes = (size_t)NB * HH * WW * 32;    // 8 MB of records
    uint4*    rec     = (uint4*)ws;
    float4*   nodes   = (float4*)(ws + rec_bytes);
    float*    partial = (float*)(ws + rec_bytes + (size_t)NB * NN * sizeof(float4));
    unsigned* cnt     = (unsigned*)(partial + NB * 256);

    Flt flt;
    {
        float g[13];
        float s = 0.f;
        for (int i = 0; i < 13; ++i) {
            float xx = (float)(i - 6);
            g[i] = expf(-xx * xx / 8.f);
            s += g[i];
        }
        for (int i = 0; i < 13; ++i) {
            flt.g[i]  = g[i] / s;
            flt.dg[i] = -(float)(i - 6) / 4.f * flt.g[i];
        }
    }

    conv_fused_kernel<<<NB * 64, 256, 0, stream>>>(pd, rec, flt);
    snake_kernel<<<NB, NN, 0, stream>>>(rec, node_pos, widths, nodes, cnt);
    render_loss_kernel<<<NB * 256, 256, 0, stream>>>(pd, nodes, partial, cnt, out);
}